// Round 1
// baseline (84.273 us; speedup 1.0000x reference)
//
#include <hip/hip_runtime.h>
#include <math.h>

#define NQ   12
#define DIM  4096
#define BLK  256
#define IND  768
#define HD   24
#define NOBS 28

// Composed CNOT-ring permutation (state_new[j] = state_old[perm(j)]).
// Ring: CNOT(0,1),CNOT(1,2),...,CNOT(11,0); qubit q <-> bit (11-q).
// Linear over GF(2): perm(x) = x ^ (x>>1) ^ ((x&1)?0xC00:0).
__device__ __forceinline__ int ringperm(int x) {
    return x ^ (x >> 1) ^ ((x & 1) ? 0xC00 : 0);
}
// LDS slot swizzle (bank-conflict fix): amplitude i lives at slot(i).
__device__ __forceinline__ int slotf(int x) { return x ^ ((x >> 4) & 15); }

// Apply 2x2 complex M=[[m00,m01],[m10,m11]] to pair (u,w).
__device__ __forceinline__ void cpair(float2& u, float2& w, const float* M) {
    float ur = u.x, ui = u.y, wr = w.x, wi = w.y;
    u.x = M[0]*ur - M[1]*ui + M[2]*wr - M[3]*wi;
    u.y = M[0]*ui + M[1]*ur + M[2]*wi + M[3]*wr;
    w.x = M[4]*ur - M[5]*ui + M[6]*wr - M[7]*wi;
    w.y = M[4]*ui + M[5]*ur + M[6]*wi + M[7]*wr;
}

__global__ void __launch_bounds__(BLK) pqm_kernel(
    const float* __restrict__ x,   const float* __restrict__ W1,
    const float* __restrict__ b1,  const float* __restrict__ ln_g,
    const float* __restrict__ ln_b,const float* __restrict__ W2,
    const float* __restrict__ b2,  const float* __restrict__ qw0,
    const float* __restrict__ qw1, const float* __restrict__ qw2,
    const float* __restrict__ scales, const float* __restrict__ biases,
    float* __restrict__ out)
{
    __shared__ float2 st[DIM];          // 32 KB statevector (swizzled slots)
    __shared__ float  hbuf[HD];
    __shared__ float  Rm[3][NQ][8];     // Rot matrices per layer/qubit
    __shared__ float  Ml[3][NQ][8];     // fused M = Rot*RY
    __shared__ float  angc[NQ], angs[NQ];
    __shared__ float  red[NOBS * 4];

    const int t   = threadIdx.x;
    const int row = blockIdx.x;

    // ---- Phase 1: stage x row into LDS (reuse state buffer) ----
    float* xs = (float*)st;
    for (int k = t; k < IND; k += BLK) xs[k] = x[row * IND + k];
    __syncthreads();

    // ---- Phase 2: h = x@W1^T + b1 (24 outs, 8 lanes each); Rot mats ----
    {
        int g = t >> 3, l8 = t & 7;
        if (g < HD) {
            const float* w = W1 + g * IND;
            float acc = 0.f;
            for (int k = l8; k < IND; k += 8) acc += xs[k] * w[k];
            acc += __shfl_down(acc, 4, 8);
            acc += __shfl_down(acc, 2, 8);
            acc += __shfl_down(acc, 1, 8);
            if (l8 == 0) hbuf[g] = acc + b1[g];
        } else if (t >= 192 && t < 192 + 3 * NQ) {
            int li = (t - 192) / NQ, q = (t - 192) % NQ;
            const float* qw = (li == 0) ? qw0 : ((li == 1) ? qw1 : qw2);
            float phi = qw[q*3+0], th = qw[q*3+1], om = qw[q*3+2];
            float c = cosf(0.5f*th), s = sinf(0.5f*th);
            float sp, cp, sm, cm;
            sincosf(0.5f*(phi+om), &sp, &cp);
            sincosf(0.5f*(phi-om), &sm, &cm);
            float* R = Rm[li][q];
            R[0] =  cp*c;  R[1] = -sp*c;   // a  = e^{-i(phi+om)/2} c
            R[2] = -cm*s;  R[3] = -sm*s;   // b  = -e^{+i(phi-om)/2} s
            R[4] =  cm*s;  R[5] = -sm*s;   // cc = e^{-i(phi-om)/2} s
            R[6] =  cp*c;  R[7] =  sp*c;   // d  = e^{+i(phi+om)/2} c
        }
    }
    __syncthreads();

    // ---- Phase 3: LN + ReLU + W2 + tanh -> angles (t<12); zero state ----
    if (t < NQ) {
        float mu = 0.f;
        #pragma unroll
        for (int j = 0; j < HD; ++j) mu += hbuf[j];
        mu *= (1.f / HD);
        float var = 0.f;
        #pragma unroll
        for (int j = 0; j < HD; ++j) { float d = hbuf[j] - mu; var += d * d; }
        var *= (1.f / HD);
        float rinv = 1.f / sqrtf(var + 1e-5f);
        float acc = b2[t];
        #pragma unroll
        for (int j = 0; j < HD; ++j) {
            float hn = (hbuf[j] - mu) * rinv * ln_g[j] + ln_b[j];
            acc += fmaxf(hn, 0.f) * W2[t * HD + j];
        }
        float a = tanhf(acc);
        angc[t] = cosf(0.5f * a);
        angs[t] = sinf(0.5f * a);
    }
    // zero state; |0...0> amplitude = 1 (slot(0)==0). Safe: dot readers done.
    for (int i = t; i < DIM; i += BLK)
        st[i] = (i == 0) ? make_float2(1.f, 0.f) : make_float2(0.f, 0.f);
    __syncthreads();

    // ---- Phase 4: fused per-qubit gate M = Rot * RY ----
    if (t < 3 * NQ) {
        int li = t / NQ, q = t % NQ;
        float cr = angc[q], sr = angs[q];
        const float* R = Rm[li][q];
        float* M = Ml[li][q];
        M[0] =  R[0]*cr + R[2]*sr;  M[1] =  R[1]*cr + R[3]*sr;
        M[2] = -R[0]*sr + R[2]*cr;  M[3] = -R[1]*sr + R[3]*cr;
        M[4] =  R[4]*cr + R[6]*sr;  M[5] =  R[5]*cr + R[7]*sr;
        M[6] = -R[4]*sr + R[6]*cr;  M[7] = -R[5]*sr + R[7]*cr;
    }
    __syncthreads();

    auto butterflies = [&](float2* v, const float (*Mlayer)[8], int qtop) {
        #pragma unroll
        for (int j = 0; j < 4; ++j) {
            float Mq[8];
            const float* Msrc = Mlayer[qtop - j];
            #pragma unroll
            for (int u = 0; u < 8; ++u) Mq[u] = Msrc[u];
            #pragma unroll
            for (int r = 0; r < 16; ++r)
                if (!(r & (1 << j))) cpair(v[r], v[r | (1 << j)], Mq);
        }
    };

    // ---- Circuit: 3 layers x 3 register passes; CNOT rings folded ----
    for (int l = 0; l < 3; ++l) {
        const float (*M)[8] = Ml[l];
        float2 v[16];
        // pass A: idx bits 0..3 in registers (qubits 11..8)
        {
            int tb = t << 4, x4 = t & 15;
            if (l == 0) {
                #pragma unroll
                for (int r = 0; r < 16; ++r) v[r] = st[tb | (r ^ x4)];
            } else {
                // fold previous layer's CNOT ring: gather from perm(idx)
                #pragma unroll
                for (int r = 0; r < 16; ++r)
                    v[r] = st[slotf(ringperm(tb | r))];
                __syncthreads();   // all gathers before any scatter
            }
            butterflies(v, M, 11);
            #pragma unroll
            for (int r = 0; r < 16; ++r) st[tb | (r ^ x4)] = v[r];
        }
        __syncthreads();
        // pass B: idx bits 4..7 in registers (qubits 7..4)
        {
            int hi8 = (t >> 4) << 8, lo4 = t & 15;
            #pragma unroll
            for (int r = 0; r < 16; ++r) v[r] = st[hi8 | (r << 4) | (lo4 ^ r)];
            butterflies(v, M, 7);
            #pragma unroll
            for (int r = 0; r < 16; ++r) st[hi8 | (r << 4) | (lo4 ^ r)] = v[r];
        }
        __syncthreads();
        // pass C: idx bits 8..11 in registers (qubits 3..0)
        {
            int tc = t ^ ((t >> 4) & 15);
            #pragma unroll
            for (int r = 0; r < 16; ++r) v[r] = st[(r << 8) | tc];
            butterflies(v, M, 3);
            #pragma unroll
            for (int r = 0; r < 16; ++r) st[(r << 8) | tc] = v[r];
        }
        __syncthreads();
    }

    // ---- Measurement (final ring folded via perm-gather) ----
    {
        float2 v[16];
        const int tpart = ((t >> 7) << 11) | (t & 127);  // idx bits 7..10 <- k
        float accZ[NQ], accZZ[NQ - 1], accX[5];
        #pragma unroll
        for (int q = 0; q < NQ; ++q) accZ[q] = 0.f;
        #pragma unroll
        for (int q = 0; q < NQ - 1; ++q) accZZ[q] = 0.f;
        #pragma unroll
        for (int q = 0; q < 5; ++q) accX[q] = 0.f;

        #pragma unroll
        for (int k = 0; k < 16; ++k) {
            int idx  = tpart | (k << 7);
            int base = ringperm(idx);
            int s0   = slotf(base);
            v[k] = st[s0];
            float pr = v[k].x * v[k].x + v[k].y * v[k].y;
            float z[NQ];
            #pragma unroll
            for (int q = 0; q < NQ; ++q)
                z[q] = ((idx >> (11 - q)) & 1) ? -1.f : 1.f;
            #pragma unroll
            for (int q = 0; q < NQ; ++q) accZ[q] += pr * z[q];
            #pragma unroll
            for (int q = 0; q < NQ - 1; ++q) accZZ[q] += pr * z[q] * z[q + 1];
            // eX[0] (bit 11): partner; perm(idx^0x800)=perm(idx)^0xC00,
            // sdelta(0xC00)=0xC00. Double-count over threads == required 2x.
            float2 w = st[s0 ^ 0xC00];
            accX[0] += v[k].x * w.x + v[k].y * w.y;
        }
        #pragma unroll
        for (int q = 1; q < 5; ++q) {      // eX[q], pos 11-q -> k-bit 4-q
            int jb = 4 - q;
            #pragma unroll
            for (int k = 0; k < 16; ++k)
                if (!(k & (1 << jb))) {
                    int kp = k | (1 << jb);
                    accX[q] += v[k].x * v[kp].x + v[k].y * v[kp].y;
                }
        }

        float obs[NOBS];
        #pragma unroll
        for (int q = 0; q < NQ; ++q) obs[q] = accZ[q];
        #pragma unroll
        for (int q = 0; q < NQ - 1; ++q) obs[NQ + q] = accZZ[q];
        obs[23] = accX[0];                      // already 2x via double count
        #pragma unroll
        for (int q = 1; q < 5; ++q) obs[23 + q] = 2.f * accX[q];

        int lane = t & 63, wv = t >> 6;
        #pragma unroll
        for (int o = 0; o < NOBS; ++o) {
            float s = obs[o];
            #pragma unroll
            for (int d = 32; d; d >>= 1) s += __shfl_down(s, d, 64);
            if (lane == 0) red[o * 4 + wv] = s;
        }
        __syncthreads();
        if (t < NOBS) {
            float s = red[t*4] + red[t*4+1] + red[t*4+2] + red[t*4+3];
            out[row * NOBS + t] = s * scales[t] + biases[t];
        }
    }
}

extern "C" void kernel_launch(void* const* d_in, const int* in_sizes, int n_in,
                              void* d_out, int out_size, void* d_ws, size_t ws_size,
                              hipStream_t stream) {
    const int Bn = in_sizes[0] / IND;   // 1024
    pqm_kernel<<<dim3(Bn), dim3(BLK), 0, stream>>>(
        (const float*)d_in[0], (const float*)d_in[1], (const float*)d_in[2],
        (const float*)d_in[3], (const float*)d_in[4], (const float*)d_in[5],
        (const float*)d_in[6], (const float*)d_in[7], (const float*)d_in[8],
        (const float*)d_in[9], (const float*)d_in[10], (const float*)d_in[11],
        (float*)d_out);
}

// Round 2
// 46.244 us; speedup vs baseline: 1.8223x; 1.8223x over previous
//
#include <hip/hip_runtime.h>
#include <math.h>

#define NQ   12
#define DIM  4096
#define BLK  256
#define IND  768
#define HD   24
#define NOBS 28

typedef float f32x2 __attribute__((ext_vector_type(2)));

// Composed CNOT-ring permutation (state_new[j] = state_old[perm(j)]).
// Ring: CNOT(0,1),...,CNOT(11,0); qubit q <-> bit (11-q).
__device__ __forceinline__ int ringperm(int x) {
    return x ^ (x >> 1) ^ ((x & 1) ? 0xC00 : 0);
}
// LDS slot swizzle (bank-conflict fix): amplitude i lives at slot(i).
__device__ __forceinline__ int slotf(int x) { return x ^ ((x >> 4) & 15); }

// ---- packed complex arithmetic (VOP3P, 2 FMA per instruction) ----
// m = (re, im) of gate entry; u = (re, im) amplitude.
// cmul: r = m*u : r.x = m.x*u.x - m.y*u.y ; r.y = m.x*u.y + m.y*u.x
__device__ __forceinline__ f32x2 pk_cmul(f32x2 m, f32x2 u) {
    f32x2 r;
    asm("v_pk_mul_f32 %0, %1, %2 op_sel:[0,0] op_sel_hi:[0,1]"
        : "=v"(r) : "v"(m), "v"(u));
    asm("v_pk_fma_f32 %0, %1, %2, %0 op_sel:[1,1,0] op_sel_hi:[1,0,1] neg_lo:[0,1,0]"
        : "+v"(r) : "v"(m), "v"(u));
    return r;
}
__device__ __forceinline__ void pk_cfma(f32x2& acc, f32x2 m, f32x2 u) {
    asm("v_pk_fma_f32 %0, %1, %2, %0 op_sel:[0,0,0] op_sel_hi:[0,1,1]"
        : "+v"(acc) : "v"(m), "v"(u));
    asm("v_pk_fma_f32 %0, %1, %2, %0 op_sel:[1,1,0] op_sel_hi:[1,0,1] neg_lo:[0,1,0]"
        : "+v"(acc) : "v"(m), "v"(u));
}
// plain elementwise packed fma: acc += a*b (both halves independently)
__device__ __forceinline__ void pk_fma_plain(f32x2& acc, f32x2 a, f32x2 b) {
    asm("v_pk_fma_f32 %0, %1, %2, %0" : "+v"(acc) : "v"(a), "v"(b));
}

__global__ void __launch_bounds__(BLK) pqm_kernel(
    const float* __restrict__ x,   const float* __restrict__ W1,
    const float* __restrict__ b1,  const float* __restrict__ ln_g,
    const float* __restrict__ ln_b,const float* __restrict__ W2,
    const float* __restrict__ b2,  const float* __restrict__ qw0,
    const float* __restrict__ qw1, const float* __restrict__ qw2,
    const float* __restrict__ scales, const float* __restrict__ biases,
    float* __restrict__ out)
{
    __shared__ f32x2 st[DIM];           // 32 KB statevector (swizzled slots)
    __shared__ float hbuf[HD];
    __shared__ float Rm[3][NQ][8];      // Rot matrices per layer/qubit
    __shared__ float Ml[3][NQ][8];      // fused M = Rot*RY (as 4 complex pairs)
    __shared__ float angc[NQ], angs[NQ];
    __shared__ float red[4][24];        // per-wave partials

    const int t   = threadIdx.x;
    const int row = blockIdx.x;

    // ---- Phase 1: stage x row into LDS (reuse state buffer) ----
    float* xs = (float*)st;
    for (int k = t; k < IND; k += BLK) xs[k] = x[row * IND + k];
    __syncthreads();

    // ---- Phase 2: h = x@W1^T + b1 (24 outs, 8 lanes each); Rot mats ----
    {
        int g = t >> 3, l8 = t & 7;
        if (g < HD) {
            const float* w = W1 + g * IND;
            float acc = 0.f;
            for (int k = l8; k < IND; k += 8) acc += xs[k] * w[k];
            acc += __shfl_down(acc, 4, 8);
            acc += __shfl_down(acc, 2, 8);
            acc += __shfl_down(acc, 1, 8);
            if (l8 == 0) hbuf[g] = acc + b1[g];
        } else if (t >= 192 && t < 192 + 3 * NQ) {
            int li = (t - 192) / NQ, q = (t - 192) % NQ;
            const float* qw = (li == 0) ? qw0 : ((li == 1) ? qw1 : qw2);
            float phi = qw[q*3+0], th = qw[q*3+1], om = qw[q*3+2];
            float c = cosf(0.5f*th), s = sinf(0.5f*th);
            float sp, cp, sm, cm;
            sincosf(0.5f*(phi+om), &sp, &cp);
            sincosf(0.5f*(phi-om), &sm, &cm);
            float* R = Rm[li][q];
            R[0] =  cp*c;  R[1] = -sp*c;
            R[2] = -cm*s;  R[3] = -sm*s;
            R[4] =  cm*s;  R[5] = -sm*s;
            R[6] =  cp*c;  R[7] =  sp*c;
        }
    }
    __syncthreads();

    // ---- Phase 3: LN + ReLU + W2 + tanh -> angles (t<12); zero state ----
    if (t < NQ) {
        float mu = 0.f;
        #pragma unroll
        for (int j = 0; j < HD; ++j) mu += hbuf[j];
        mu *= (1.f / HD);
        float var = 0.f;
        #pragma unroll
        for (int j = 0; j < HD; ++j) { float d = hbuf[j] - mu; var += d * d; }
        var *= (1.f / HD);
        float rinv = 1.f / sqrtf(var + 1e-5f);
        float acc = b2[t];
        #pragma unroll
        for (int j = 0; j < HD; ++j) {
            float hn = (hbuf[j] - mu) * rinv * ln_g[j] + ln_b[j];
            acc += fmaxf(hn, 0.f) * W2[t * HD + j];
        }
        float a = tanhf(acc);
        angc[t] = cosf(0.5f * a);
        angs[t] = sinf(0.5f * a);
    }
    for (int i = t; i < DIM; i += BLK) {
        f32x2 z; z.x = (i == 0) ? 1.f : 0.f; z.y = 0.f;
        st[i] = z;
    }
    __syncthreads();

    // ---- Phase 4: fused per-qubit gate M = Rot * RY ----
    if (t < 3 * NQ) {
        int li = t / NQ, q = t % NQ;
        float cr = angc[q], sr = angs[q];
        const float* R = Rm[li][q];
        float* M = Ml[li][q];
        M[0] =  R[0]*cr + R[2]*sr;  M[1] =  R[1]*cr + R[3]*sr;
        M[2] = -R[0]*sr + R[2]*cr;  M[3] = -R[1]*sr + R[3]*cr;
        M[4] =  R[4]*cr + R[6]*sr;  M[5] =  R[5]*cr + R[7]*sr;
        M[6] = -R[4]*sr + R[6]*cr;  M[7] = -R[5]*sr + R[7]*cr;
    }
    __syncthreads();

    auto butterflies = [&](f32x2* v, const float (*Mlayer)[8], int qtop) {
        #pragma unroll
        for (int j = 0; j < 4; ++j) {
            const f32x2* Msrc = (const f32x2*)Mlayer[qtop - j];
            f32x2 M0 = Msrc[0], M1 = Msrc[1], M2 = Msrc[2], M3 = Msrc[3];
            #pragma unroll
            for (int r = 0; r < 16; ++r)
                if (!(r & (1 << j))) {
                    f32x2 u = v[r], w = v[r | (1 << j)];
                    f32x2 un = pk_cmul(M0, u); pk_cfma(un, M1, w);
                    f32x2 wn = pk_cmul(M2, u); pk_cfma(wn, M3, w);
                    v[r] = un; v[r | (1 << j)] = wn;
                }
        }
    };

    // ---- Circuit: 3 layers x 3 register passes; CNOT rings folded ----
    for (int l = 0; l < 3; ++l) {
        const float (*M)[8] = Ml[l];
        f32x2 v[16];
        // pass A: idx bits 0..3 in registers (qubits 11..8)
        {
            int tb = t << 4, x4 = t & 15;
            if (l == 0) {
                #pragma unroll
                for (int r = 0; r < 16; ++r) v[r] = st[tb | (r ^ x4)];
            } else {
                #pragma unroll
                for (int r = 0; r < 16; ++r)
                    v[r] = st[slotf(ringperm(tb | r))];
                __syncthreads();   // all gathers before any scatter
            }
            butterflies(v, M, 11);
            #pragma unroll
            for (int r = 0; r < 16; ++r) st[tb | (r ^ x4)] = v[r];
        }
        __syncthreads();
        // pass B: idx bits 4..7 in registers (qubits 7..4)
        {
            int hi8 = (t >> 4) << 8, lo4 = t & 15;
            #pragma unroll
            for (int r = 0; r < 16; ++r) v[r] = st[hi8 | (r << 4) | (lo4 ^ r)];
            butterflies(v, M, 7);
            #pragma unroll
            for (int r = 0; r < 16; ++r) st[hi8 | (r << 4) | (lo4 ^ r)] = v[r];
        }
        __syncthreads();
        // pass C: idx bits 8..11 in registers (qubits 3..0)
        {
            int tc = t ^ ((t >> 4) & 15);
            #pragma unroll
            for (int r = 0; r < 16; ++r) v[r] = st[(r << 8) | tc];
            butterflies(v, M, 3);
            #pragma unroll
            for (int r = 0; r < 16; ++r) st[(r << 8) | tc] = v[r];
        }
        __syncthreads();
    }

    // ---- Measurement (final ring folded via perm-gather) ----
    {
        f32x2 v[16];
        float pr[16];
        const int tpart = ((t >> 7) << 11) | (t & 127);  // idx bits 7..10 <- k
        f32x2 ax0; ax0.x = 0.f; ax0.y = 0.f;

        #pragma unroll
        for (int k = 0; k < 16; ++k) {
            int idx  = tpart | (k << 7);
            int s0   = slotf(ringperm(idx));
            v[k] = st[s0];
            pr[k] = v[k].x * v[k].x + v[k].y * v[k].y;
            // eX[0] (bit 11): partner read; double-count over threads == 2x
            f32x2 w = st[s0 ^ 0xC00];
            pk_fma_plain(ax0, v[k], w);
        }

        // in-place 16-pt Walsh-Hadamard over k bits: pr[mask] = sum pr_k * prod(-1)^{k_b}
        #pragma unroll
        for (int lev = 0; lev < 4; ++lev)
            #pragma unroll
            for (int m = 0; m < 16; ++m)
                if (!(m & (1 << lev))) {
                    float A = pr[m], Bv = pr[m | (1 << lev)];
                    pr[m] = A + Bv; pr[m | (1 << lev)] = A - Bv;
                }
        // k bit j <-> idx bit 7+j <-> qubit 4-j
        // T(q1)=pr[8] T(q2)=pr[4] T(q3)=pr[2] T(q4)=pr[1]
        // T(q1q2)=pr[12] T(q2q3)=pr[6] T(q3q4)=pr[3] ; S=pr[0]

        // eX[1..4]: pairs within k over bit (4-q)
        f32x2 axp0, axp1, axp2, axp3;
        axp0.x=0;axp0.y=0;axp1.x=0;axp1.y=0;axp2.x=0;axp2.y=0;axp3.x=0;axp3.y=0;
        #pragma unroll
        for (int k = 0; k < 16; ++k) {
            if (!(k & 8)) pk_fma_plain(axp0, v[k], v[k | 8]);   // q=1
            if (!(k & 4)) pk_fma_plain(axp1, v[k], v[k | 4]);   // q=2
            if (!(k & 2)) pk_fma_plain(axp2, v[k], v[k | 2]);   // q=3
            if (!(k & 1)) pk_fma_plain(axp3, v[k], v[k | 1]);   // q=4
        }

        const int lane = t & 63, wv = t >> 6;
        auto wsum = [&](float s) {
            #pragma unroll
            for (int d = 1; d < 64; d <<= 1) s += __shfl_xor(s, d, 64);
            return s;
        };

        float Tq[7] = {pr[8], pr[4], pr[2], pr[1], pr[12], pr[6], pr[3]};
        #pragma unroll
        for (int i = 0; i < 7; ++i) {
            float s = wsum(Tq[i]);
            if (lane == 0) red[wv][i] = s;
        }
        float aX[5] = {ax0.x + ax0.y,
                       2.f * (axp0.x + axp0.y), 2.f * (axp1.x + axp1.y),
                       2.f * (axp2.x + axp2.y), 2.f * (axp3.x + axp3.y)};
        #pragma unroll
        for (int i = 0; i < 5; ++i) {
            float s = wsum(aX[i]);
            if (lane == 0) red[wv][19 + i] = s;
        }
        // shuffle-WHT of S over 6 lane bits: lane m ends with
        // sum_t (-1)^{popcnt(m&t)} S_t   (lane bit j <-> qubit 11-j)
        float sv = pr[0];
        #pragma unroll
        for (int lev = 0; lev < 6; ++lev) {
            float o = __shfl_xor(sv, 1 << lev, 64);
            sv = (lane & (1 << lev)) ? (o - sv) : (sv + o);
        }
        const int SM[12] = {0,1,2,3,4,6,8,12,16,24,32,48};
        #pragma unroll
        for (int i = 0; i < 12; ++i)
            if (lane == SM[i]) red[wv][7 + i] = sv;
        __syncthreads();

        if (t < NOBS) {
            // slot per observable (see derivation):
            // eZ: 0:S(sgn q0) 1..4:T(q1..q4) 5:S(sgn q5) 6..11:S(32,16,8,4,2,1)
            // eZZ: (0,1):T(q1)sgn0 (1,2):T12 (2,3):T23 (3,4):T34 (4,5):T(q4)sgn5
            //      (5,6):S32 sgn5 (6,7):S48 (7,8):S24 (8,9):S12 (9,10):S6 (10,11):S3
            const int oslot[NOBS] = {7,0,1,2,3,7,17,15,13,11,9,8,
                                     0,4,5,6,3,17,18,16,14,12,10,
                                     19,20,21,22,23};
            // sign source: 0 none, 1 = wave bit0 (qubit5), 2 = wave bit1 (qubit0)
            const int osign[NOBS] = {2,0,0,0,0,1,0,0,0,0,0,0,
                                     2,0,0,0,1,1,0,0,0,0,0,
                                     0,0,0,0,0};
            int sl = oslot[t], sg = osign[t];
            float s = 0.f;
            #pragma unroll
            for (int w = 0; w < 4; ++w) {
                float p = red[w][sl];
                bool flip = (sg == 1 && (w & 1)) || (sg == 2 && (w & 2));
                s += flip ? -p : p;
            }
            out[row * NOBS + t] = s * scales[t] + biases[t];
        }
    }
}

extern "C" void kernel_launch(void* const* d_in, const int* in_sizes, int n_in,
                              void* d_out, int out_size, void* d_ws, size_t ws_size,
                              hipStream_t stream) {
    const int Bn = in_sizes[0] / IND;   // 1024
    pqm_kernel<<<dim3(Bn), dim3(BLK), 0, stream>>>(
        (const float*)d_in[0], (const float*)d_in[1], (const float*)d_in[2],
        (const float*)d_in[3], (const float*)d_in[4], (const float*)d_in[5],
        (const float*)d_in[6], (const float*)d_in[7], (const float*)d_in[8],
        (const float*)d_in[9], (const float*)d_in[10], (const float*)d_in[11],
        (float*)d_out);
}